// Round 5
// baseline (473.761 us; speedup 1.0000x reference)
//
#include <hip/hip_runtime.h>

// CTC loss forward. Probability-space DP with periodic renormalization
// (exact up to rounding for this linear recurrence) so the result stays
// finite where the naive fp32 DP overflows to inf (~2.5x mass growth per
// step, 255 steps).
// T=256, B=64, C=6000, S=32, L=2S+1=65.
//
//   ctc_dp<<<64, 256>>>: block b = batch item b.
//     - 4 waves gather the 256*33 needed probs (blank + labels) -> LDS.
//     - wave 0 runs the alpha recurrence: lane l holds alpha[l], cell 64
//       replicated in all lanes. Every 8 steps: wave-max rescale, log-scale
//       accumulated. loss = -(log(a_end + a_end1) + acc_log) / target_len.
//   ctc_reduce<<<1, 64>>>: mean over per-sample losses -> d_out[0].

#define T_ 256
#define B_ 64
#define C_ 6000
#define S_ 32
#define NK 33   // blank + S labels

__global__ __launch_bounds__(256) void ctc_dp(
    const float* __restrict__ logp,      // (T, B, C)
    const int*   __restrict__ targets,   // (B, S)
    const int*   __restrict__ in_len,    // (B,)
    const int*   __restrict__ tgt_len,   // (B,)
    float*       __restrict__ loss_out)  // (B,)
{
    __shared__ float p_lds[T_ * NK];   // 33792 B: p_lds[t*33 + k]
    __shared__ int   tcls[NK];         // class per slot: 0=blank, k+1=targets[k]

    const int b    = blockIdx.x;
    const int tid  = threadIdx.x;
    const int lane = tid & 63;
    const int wave = tid >> 6;

    if (tid == 0) tcls[0] = 0;
    if (tid < S_) tcls[tid + 1] = targets[b * S_ + tid];
    __syncthreads();

    // ---- gather phase: wave w covers flat range [w*2112, (w+1)*2112) ----
    {
        const long long row = (long long)B_ * C_;
        const long long bc  = (long long)b * C_;
        #pragma unroll 3
        for (int i = 0; i < 33; ++i) {
            int f = wave * (64 * NK) + lane + 64 * i;
            int t = f / NK;
            int k = f - t * NK;
            int c = tcls[k];
            float v = logp[(long long)t * row + bc + c];
            p_lds[f] = expf(v);
        }
    }
    __syncthreads();

    if (wave != 0) return;   // DP on wave 0 only; no barriers after this

    // ---- per-lane DP constants ----
    const int tl  = tgt_len[b];          // uniform
    const int il  = in_len[b];           // uniform
    const int odd = lane & 1;
    const int k   = lane >> 1;
    const int idx = (odd && k < tl) ? (k + 1) : 0;        // prob slot for cell l
    const int tp_me = (odd && k < tl) ? tcls[k + 1] : 0;  // extended label at l
    const int tp_m2 = (odd && k >= 1 && (k - 1) < tl) ? tcls[k] : 0; // label l-2
    const bool m3 = (lane >= 2) && (tp_me != tp_m2);      // skip allowed

    // init: alpha0[0]=p(t0,blank), alpha0[1]=p(t0,label0), rest 0; cell64=0
    float alpha = (lane < 2) ? p_lds[idx] : 0.0f;
    float a64 = 0.0f;
    float acc_log = 0.0f;                // accumulated log of removed scales

    // prefetched per-step probs (t=1)
    float pc  = p_lds[NK + idx];
    float pbc = p_lds[NK];          // blank prob (for cell 64)

    for (int t = 1; t < il; ++t) {
        // periodic renormalization: growth <= 3^8 between rescales, far from
        // fp32 max; shrink >= ~0.85x, far from denormals. Uniform branch.
        if ((t & 7) == 0) {
            float m = fmaxf(alpha, a64);
            #pragma unroll
            for (int off = 1; off < 64; off <<= 1)
                m = fmaxf(m, __shfl_xor(m, off));
            float rinv = 1.0f / m;       // m >= 0.98^t * scale > 0 always
            alpha *= rinv;
            a64   *= rinv;
            acc_log += logf(m);
        }
        // prefetch next step's probs (clamped; unused on final iteration)
        int tn = t + 1 < T_ ? t + 1 : T_ - 1;
        float pn  = p_lds[tn * NK + idx];
        float pbn = p_lds[tn * NK];
        float a1  = __shfl_up(alpha, 1);
        if (lane == 0) a1 = 0.0f;
        float a2  = __shfl_up(alpha, 2);
        float a63 = __shfl(alpha, 63);
        float s  = alpha + a1;
        s = s + (m3 ? a2 : 0.0f);
        float na  = pc * s;
        float n64 = pbc * (a64 + a63);   // cell 64: blank==blank, no skip
        alpha = na;
        a64   = n64;
        pc = pn; pbc = pbn;
    }

    const int end = 2 * tl;              // in [32, 64]
    float aend  = (end == 64) ? a64 : __shfl(alpha, end);
    float aend1 = __shfl(alpha, end - 1);

    if (lane == 0) {
        float loss = -(logf(aend + aend1) + acc_log);
        loss_out[b] = loss / (float)tl;
    }
}

__global__ void ctc_reduce(const float* __restrict__ loss, float* __restrict__ out)
{
    float v = loss[threadIdx.x];
    #pragma unroll
    for (int off = 32; off > 0; off >>= 1) v += __shfl_down(v, off);
    if (threadIdx.x == 0) out[0] = v * (1.0f / 64.0f);
}

extern "C" void kernel_launch(void* const* d_in, const int* in_sizes, int n_in,
                              void* d_out, int out_size, void* d_ws, size_t ws_size,
                              hipStream_t stream)
{
    const float* logp = (const float*)d_in[0];
    const int*   tgt  = (const int*)d_in[1];
    const int*   il   = (const int*)d_in[2];
    const int*   tl   = (const int*)d_in[3];
    float* wsl = (float*)d_ws;           // 64 floats of scratch

    ctc_dp<<<B_, 256, 0, stream>>>(logp, tgt, il, tl, wsl);
    ctc_reduce<<<1, 64, 0, stream>>>(wsl, (float*)d_out);
}